// Round 11
// baseline (93.581 us; speedup 1.0000x reference)
//
#include <hip/hip_runtime.h>
#include <hip/hip_bf16.h>

// E_s = 0.5 * sum_{a,b,n,i,j} W[a,b,n] A[i,j,n] v[i,a,s] v[j,b,s]
// Core: t[i,n,c] = sum_j A_n[i,j] * v[j,c], c=(b,s) in [0,192); epilogue is
// linear in t -> per-block/per-wave j-partials just add.
// R11 = R8 structure with BK=128 (16 steps instead of 32 -> half the barrier
// crossings, each amortized over 2x MFMA). 1-deep prefetch (R10's 2-deep was
// neutral: __syncthreads drains vmcnt(0) regardless of depth).

typedef __attribute__((ext_vector_type(8))) short short8;   // bf16x8 frag
typedef __attribute__((ext_vector_type(4))) float floatx4;  // f32x4 acc

#define VF_U4 (12*512*16)   // uint4 elements in v fragment buffer (1.5 MB)
#define NBLK  512

__device__ __forceinline__ unsigned short f2bf(float f) {
    union { float f; unsigned u; } x; x.f = f;
    unsigned r = x.u + 0x7fffu + ((x.u >> 16) & 1u);   // RTNE
    return (unsigned short)(r >> 16);
}
__device__ __forceinline__ unsigned pack2(float lo, float hi) {
    return (unsigned)f2bf(lo) | ((unsigned)f2bf(hi) << 16);
}

// Build bf16 B-operand fragments from v[4096][3][64]:
// vf layout: [f=c/16][kb=j/8][ci=c%16][je=j%8] bf16, i.e. uint4 index
// (f*512+kb)*16+ci holds 8 consecutive j for column c. A wave's B-frag load
// (16 cols x 32 j) is 64 consecutive uint4 -> one coalesced dwordx4/lane.
__global__ void prep_vfrag(const float* __restrict__ v, uint4* __restrict__ vf) {
    int tid = blockIdx.x * 256 + threadIdx.x;
    if (tid >= VF_U4) return;
    int ci = tid & 15;
    int kb = (tid >> 4) & 511;
    int f  = tid >> 13;
    int c = f * 16 + ci;
    int b = c >> 6, s = c & 63;
    int j0 = kb * 8;
    unsigned q0 = pack2(v[((j0+0)*3+b)*64+s], v[((j0+1)*3+b)*64+s]);
    unsigned q1 = pack2(v[((j0+2)*3+b)*64+s], v[((j0+3)*3+b)*64+s]);
    unsigned q2 = pack2(v[((j0+4)*3+b)*64+s], v[((j0+5)*3+b)*64+s]);
    unsigned q3 = pack2(v[((j0+6)*3+b)*64+s], v[((j0+7)*3+b)*64+s]);
    vf[tid] = make_uint4(q0, q1, q2, q3);
}

// Main: 512 blocks = 256 i-tiles (16 rows) x 2 j-halves (2048 each).
// 512 threads = 8 waves: wave w -> kh=w>>2 (64-j half of BK=128), ws=w&3
// (48-col slice). Per wave per step: 8 A ds_read_b128, 6 B dwordx4, 24 MFMA.
// LDS: 2 bufs x 4 n x 16 rows x 256 B (128 j bf16), 16B granules XOR-swizzled
// by 4-bit row (reads 2-way = free; staging writes ~4-way on b64s only).
__global__ __launch_bounds__(512, 2) void energy_main(
        const float* __restrict__ A, const float* __restrict__ v,
        const float* __restrict__ W, const uint4* __restrict__ vf,
        float* __restrict__ partials) {
    __shared__ __align__(16) unsigned As32[8192];   // 32 KB
    __shared__ float Wl[36];
    __shared__ float El[64];

    const int tid = threadIdx.x;
    const int bid = blockIdx.x;
    const int ib = bid >> 1, jh = bid & 1;
    const int i0 = ib * 16;
    const int jbase = jh * 2048;

    if (tid < 36) Wl[tid] = W[tid];
    if (tid < 64) El[tid] = 0.0f;

    const int lane = tid & 63;
    const int w = tid >> 6;
    const int kh = w >> 2;
    const int ws = w & 3;

    // ---- staging indices: r = row 0..15, jp = 0..31 -> j-quad 4jp..4jp+3
    const int r  = tid >> 5;
    const int jp = tid & 31;
    const long arowBase = (long)(i0 + r) * 4096 + jbase + 4 * jp;  // float4 units
    // u32 idx within an n-plane: row*64 + swizzled-granule*4 + sub
    const int aWrIdx = r * 64 + (((jp >> 1) ^ (r & 15)) << 2) + ((jp & 1) << 1);

    // ---- A-frag read: row rr, logical granule gj = kh*8 + kc*4 + g4
    const int rr = lane & 15;
    const int g4 = lane >> 4;
    const int aRdRow = rr * 256;               // bytes within n-plane

    // ---- B-frag base (uint4 kb units of 8 j)
    const int kbBase = (jbase >> 3) + kh * 8;  // + kc*4 + t*16

    floatx4 acc[4][3];
    #pragma unroll
    for (int n = 0; n < 4; ++n)
        #pragma unroll
        for (int cf = 0; cf < 3; ++cf)
            #pragma unroll
            for (int q = 0; q < 4; ++q) acc[n][cf][q] = 0.0f;

    const floatx4* A4 = reinterpret_cast<const floatx4*>(A);

    // ---- prologue: stage tile 0 into buf 0
    {
        floatx4 na[4];
        #pragma unroll
        for (int q = 0; q < 4; ++q) na[q] = A4[arowBase + q];
        #pragma unroll
        for (int n = 0; n < 4; ++n) {
            uint2 w2 = make_uint2(pack2(na[0][n], na[1][n]),
                                  pack2(na[2][n], na[3][n]));
            *reinterpret_cast<uint2*>(&As32[n * 1024 + aWrIdx]) = w2;
        }
    }

    int cur = 0;
    for (int t = 0; t < 16; ++t) {
        __syncthreads();                       // buf[cur] writes visible
        floatx4 na[4];
        if (t < 15) {                          // issue next-tile loads early
            long o = arowBase + (long)(t + 1) * 128;
            #pragma unroll
            for (int q = 0; q < 4; ++q) na[q] = A4[o + q];
        }
        const char* abase = reinterpret_cast<const char*>(As32) + cur * 16384;
        #pragma unroll
        for (int kc = 0; kc < 2; ++kc) {
            short8 bc[3];
            #pragma unroll
            for (int cf = 0; cf < 3; ++cf) {
                int kb = kbBase + kc * 4 + t * 16;
                bc[cf] = *reinterpret_cast<const short8*>(
                    vf + ((ws * 3 + cf) * 512 + kb) * 16 + lane);
            }
            short8 af[4];
            const int gOff = (((kh << 3) + (kc << 2) + g4) ^ (rr & 15)) << 4;
            #pragma unroll
            for (int n = 0; n < 4; ++n)
                af[n] = *reinterpret_cast<const short8*>(
                    abase + n * 4096 + aRdRow + gOff);
            #pragma unroll
            for (int n = 0; n < 4; ++n)
                #pragma unroll
                for (int cf = 0; cf < 3; ++cf)
                    acc[n][cf] = __builtin_amdgcn_mfma_f32_16x16x32_bf16(
                        af[n], bc[cf], acc[n][cf], 0, 0, 0);
        }
        __syncthreads();                       // all reads of buf[cur] done
        if (t < 15) {
            unsigned* dst = &As32[(cur ^ 1) * 4096];
            #pragma unroll
            for (int n = 0; n < 4; ++n) {
                uint2 w2 = make_uint2(pack2(na[0][n], na[1][n]),
                                      pack2(na[2][n], na[3][n]));
                *reinterpret_cast<uint2*>(&dst[n * 1024 + aWrIdx]) = w2;
            }
        }
        cur ^= 1;
    }

    // ---- epilogue: E_partial[s] += t[i,n,c] * P[i,n,c], P = sum_a W[a,b,n] v[i,a,s]
    // C layout: col = lane&15 (c within frag), row = (lane>>4)*4 + reg
    float cont[3];
    #pragma unroll
    for (int cf = 0; cf < 3; ++cf) {
        int c = ws * 48 + cf * 16 + rr;
        int b = c >> 6, s = c & 63;
        float sum = 0.0f;
        #pragma unroll
        for (int rg = 0; rg < 4; ++rg) {
            int i = i0 + (lane >> 4) * 4 + rg;
            float v0 = v[(i * 3 + 0) * 64 + s];
            float v1 = v[(i * 3 + 1) * 64 + s];
            float v2 = v[(i * 3 + 2) * 64 + s];
            #pragma unroll
            for (int n = 0; n < 4; ++n) {
                float P = Wl[b * 4 + n] * v0 + Wl[12 + b * 4 + n] * v1
                        + Wl[24 + b * 4 + n] * v2;
                sum += acc[n][cf][rg] * P;
            }
        }
        cont[cf] = sum;
    }
    #pragma unroll
    for (int cf = 0; cf < 3; ++cf) {           // sum the 4 i-groups (same c)
        cont[cf] += __shfl_xor(cont[cf], 16);
        cont[cf] += __shfl_xor(cont[cf], 32);
    }
    __syncthreads();
    if (lane < 16) {
        #pragma unroll
        for (int cf = 0; cf < 3; ++cf) {
            int s = (ws * 48 + cf * 16 + lane) & 63;
            atomicAdd(&El[s], cont[cf]);       // LDS atomics, block-local
        }
    }
    __syncthreads();
    if (tid < 64) partials[bid * 64 + tid] = 0.5f * El[tid];
}

// 512 threads: chunk = tid>>6 (8 chunks), s = tid&63; fixed order -> deterministic
__global__ void reduce_out(const float* __restrict__ partials, float* __restrict__ out) {
    __shared__ float red[8][64];
    int tid = threadIdx.x;
    int chunk = tid >> 6, s = tid & 63;
    float a = 0.0f;
    for (int m = 0; m < NBLK / 8; ++m)
        a += partials[((m << 3) + chunk) * 64 + s];
    red[chunk][s] = a;
    __syncthreads();
    if (tid < 64) {
        float t = 0.0f;
        #pragma unroll
        for (int c = 0; c < 8; ++c) t += red[c][tid];
        out[tid] = t;
    }
}

extern "C" void kernel_launch(void* const* d_in, const int* in_sizes, int n_in,
                              void* d_out, int out_size, void* d_ws, size_t ws_size,
                              hipStream_t stream) {
    const float* W = (const float*)d_in[0];   // [3][3][4]
    const float* A = (const float*)d_in[1];   // [4096][4096][4]
    const float* v = (const float*)d_in[2];   // [4096][3][64]
    float* out = (float*)d_out;               // [64] f32
    uint4* vf = (uint4*)d_ws;                                  // 1.5 MB
    float* partials = (float*)((char*)d_ws + (size_t)VF_U4 * 16); // +128 KB

    hipLaunchKernelGGL(prep_vfrag, dim3((VF_U4 + 255) / 256), dim3(256), 0, stream, v, vf);
    hipLaunchKernelGGL(energy_main, dim3(NBLK), dim3(512), 0, stream, A, v, W, vf, partials);
    hipLaunchKernelGGL(reduce_out, dim3(1), dim3(512), 0, stream, partials, out);
}